// Round 4
// baseline (1282.838 us; speedup 1.0000x reference)
//
#include <hip/hip_runtime.h>
#include <hip/hip_bf16.h>
#include <stdint.h>

// Set Transformer forward on gfx950. Round 7.
// Changes vs R6: split-K combine fused into k_flash via last-block-done
// (atomic counter per (q-tile, head); winner combines own regs + 3 partials
// in FIXED z-order 0..3 -> bit-identical to the old k_combine). 5 combine
// launches removed (22 -> 17 dispatches). Counters zeroed each iteration by
// a tail block in k_prep (workspace is re-poisoned between iterations).
// GEMM unroll reverted to 4 (unroll 8 was null in R6).

#define HID 512
#define EMBD 768
#define NCTX 2048
#define HD 64

typedef __attribute__((ext_vector_type(8))) short v8s;   // 8 x bf16
typedef __attribute__((ext_vector_type(4))) float v4f;   // MFMA accumulator

#define MFMA(a, b, c) __builtin_amdgcn_mfma_f32_16x16x32_bf16((a), (b), (c), 0, 0, 0)

__device__ __forceinline__ short f2bf(float f) {
  return __builtin_bit_cast(short, __float2bfloat16(f));
}
__device__ __forceinline__ float bf2f(short s) {
  uint32_t u = ((uint32_t)(uint16_t)s) << 16;
  return __builtin_bit_cast(float, u);
}
__device__ __forceinline__ v8s ldbf8(const short* p) { return *(const v8s*)p; }

// ---------------- fused prep: weight convert + embedding + S + counters -----
struct ConvDesc {
  const float* src[20];
  unsigned cum[21];
};

#define NB_CONV 22016u   // 5636096 / 256
#define NB_EMB 6144u     // 2048*768 / 256
#define NB_S 128u        // 64*512 / 256

__global__ __launch_bounds__(256) void k_prep(
    ConvDesc d, short* __restrict__ Wdst,
    const int* __restrict__ is_cat, const int* __restrict__ cat_idx,
    const int* __restrict__ reg_idx, const float* __restrict__ reg_values,
    const float* __restrict__ cat_table, const float* __restrict__ reg_table,
    const float* __restrict__ reg_W, const float* __restrict__ reg_b,
    short* __restrict__ emb_out, const float* __restrict__ S,
    short* __restrict__ s_out, int* __restrict__ cnt) {
  unsigned b = blockIdx.x;
  if (b < NB_CONV) {
    unsigned i = b * 256u + threadIdx.x;
    if (i >= d.cum[20]) return;
    int t = 0;
    while (i >= d.cum[t + 1]) ++t;
    Wdst[i] = f2bf(d.src[t][i - d.cum[t]]);
  } else if (b < NB_CONV + NB_EMB) {
    int i = (int)(b - NB_CONV) * 256 + threadIdx.x;
    int n = i / EMBD, e = i - n * EMBD;
    float v;
    if (is_cat[n]) {
      v = cat_table[(long)cat_idx[n] * EMBD + e];
    } else {
      int r = reg_idx[n];
      if (e < 512) v = reg_table[r * 512 + e];
      else {
        int e2 = e - 512;
        v = reg_W[r * 256 + e2] * reg_values[n] + reg_b[r * 256 + e2];
      }
    }
    emb_out[i] = f2bf(v);
  } else if (b < NB_CONV + NB_EMB + NB_S) {
    int i = (int)(b - NB_CONV - NB_EMB) * 256 + threadIdx.x;
    int row = i >> 9;
    s_out[i] = (row < 7) ? f2bf(S[i]) : (short)0;
  } else {
    // zero the 5 x 256 split-K arrival counters (workspace is poisoned)
    for (int k = 0; k < 8; ++k) cnt[threadIdx.x * 8 + k] = 0;
  }
}

// ---------------- multi-job NT GEMM: C[M,N] = A[M,K] @ B[N,K]^T -------------
// Up to 3 independent GEMMs in one launch; blocks decode their job from a
// base offset. One wave per 32x64 tile.
// epi 0: out = (acc + (col<512 ? biasA[col] : biasB[col-512])) * (col<512?sA:sB)
// epi 1: out = acc + biasA[row]
struct GemmJob {
  const short* A;
  const short* B;
  const float* biasA;
  const float* biasB;
  short* out;
  int N, KK, epi, gx, base;
  float sA, sB;
};
struct GemmBatch {
  GemmJob j[3];
  int nj;
};

__global__ __launch_bounds__(64) void k_gemm_multi(GemmBatch gb) {
  int wg = blockIdx.x;
  int ji = 0;
  if (gb.nj > 1 && wg >= gb.j[1].base) ji = 1;
  if (gb.nj > 2 && wg >= gb.j[2].base) ji = 2;
  const GemmJob& j = gb.j[ji];
  int rel = wg - j.base;
  int bx = rel % j.gx, by = rel / j.gx;
  int l = threadIdx.x, l16 = l & 15, quad = l >> 4;
  int i0 = by * 32, n0 = bx * 64;
  const int KK = j.KK;
  const short* a0p = j.A + (i0 + l16) * KK + quad * 8;
  const short* a1p = a0p + 16 * KK;
  const short* bp = j.B + (n0 + l16) * KK + quad * 8;
  v4f acc[2][4];
  for (int g = 0; g < 2; ++g)
    for (int t = 0; t < 4; ++t) acc[g][t] = (v4f){0.f, 0.f, 0.f, 0.f};
#pragma unroll 4
  for (int k = 0; k < KK; k += 32) {
    v8s a0 = ldbf8(a0p + k);
    v8s a1 = ldbf8(a1p + k);
#pragma unroll
    for (int t = 0; t < 4; ++t) {
      v8s b = ldbf8(bp + t * 16 * KK + k);
      acc[0][t] = MFMA(a0, b, acc[0][t]);
      acc[1][t] = MFMA(a1, b, acc[1][t]);
    }
  }
  for (int g = 0; g < 2; ++g)
    for (int t = 0; t < 4; ++t) {
      int col = n0 + t * 16 + l16;
      float bc = 0.f, sc = 1.f;
      if (j.epi == 0) {
        bc = (col < 512) ? j.biasA[col] : j.biasB[col - 512];
        sc = (col < 512) ? j.sA : j.sB;
      }
      for (int r = 0; r < 4; ++r) {
        int row = i0 + g * 16 + quad * 4 + r;
        float v = acc[g][t][r];
        v = (j.epi == 0) ? (v + bc) * sc : v + j.biasA[row];
        j.out[row * j.N + col] = f2bf(v);
      }
    }
}

// ---------------- single-job GEMM with residual+relu epilogue (O-proj) ------
// out = resid + relu(acc + biasA[col])
template <int KK>
__global__ __launch_bounds__(64) void k_gemm_ff(const short* __restrict__ A,
                                               const short* __restrict__ B,
                                               const float* __restrict__ biasA,
                                               const short* __restrict__ resid,
                                               short* __restrict__ out, int N) {
  int l = threadIdx.x, l16 = l & 15, quad = l >> 4;
  int i0 = blockIdx.y * 32, n0 = blockIdx.x * 64;
  const short* a0p = A + (i0 + l16) * KK + quad * 8;
  const short* a1p = a0p + 16 * KK;
  const short* bp = B + (n0 + l16) * KK + quad * 8;
  v4f acc[2][4];
  for (int g = 0; g < 2; ++g)
    for (int t = 0; t < 4; ++t) acc[g][t] = (v4f){0.f, 0.f, 0.f, 0.f};
#pragma unroll 4
  for (int k = 0; k < KK; k += 32) {
    v8s a0 = ldbf8(a0p + k);
    v8s a1 = ldbf8(a1p + k);
#pragma unroll
    for (int t = 0; t < 4; ++t) {
      v8s b = ldbf8(bp + t * 16 * KK + k);
      acc[0][t] = MFMA(a0, b, acc[0][t]);
      acc[1][t] = MFMA(a1, b, acc[1][t]);
    }
  }
  for (int g = 0; g < 2; ++g)
    for (int t = 0; t < 4; ++t) {
      int col = n0 + t * 16 + l16;
      float bc = biasA[col];
      for (int r = 0; r < 4; ++r) {
        int row = i0 + g * 16 + quad * 4 + r;
        float v = bf2f(resid[row * N + col]) + fmaxf(acc[g][t][r] + bc, 0.f);
        out[row * N + col] = f2bf(v);
      }
    }
}

// ---------------- flash attention, split-K=4, fused combine ------------------
// Block: 256 thr = 4 waves, each wave a 16-query tile; z = key-chunk of 512.
// K is pre-scaled by log2(e)/sqrt(512) in its projection epilogue, so QK^T
// feeds exp2 directly. All 4 z-blocks of a (q-tile, head) write fp32
// partials; the LAST one (atomic arrival counter) combines in fixed z-order
// (bit-identical to the former k_combine) and writes bf16 out = Qresid + O/l.
__global__ __launch_bounds__(256) void k_flash(const short* __restrict__ Q, int qstride,
                                               const short* __restrict__ Kp, int kstride,
                                               const short* __restrict__ Vt,
                                               float* __restrict__ opart,
                                               float* __restrict__ lspart,
                                               int* __restrict__ cnt,
                                               short* __restrict__ oout) {
  __shared__ __align__(16) short Kt[64 * 64];   // XOR-swizzled 16B chunks
  __shared__ __align__(16) short Vtl[64 * 64];
  __shared__ __align__(16) short P[4][16 * 72];
  __shared__ int arrival;
  const int tid = threadIdx.x;
  const int wave = tid >> 6, l = tid & 63, l16 = l & 15, quad = l >> 4;
  const int h = blockIdx.y, D0 = h * HD;
  const int i0 = blockIdx.x * 64 + wave * 16;
  const int z = blockIdx.z, jbase = z * (NCTX / 4);

  const short* qrow = Q + (i0 + l16) * qstride + D0 + quad * 8;
  const v8s aq0 = ldbf8(qrow);
  const v8s aq1 = ldbf8(qrow + 32);

  const int sr = tid >> 2, sc0 = tid & 3, sc1 = sc0 + 4;
  const short* kg = Kp + (jbase + sr) * kstride + D0;
  const short* vg = Vt + (D0 + sr) * NCTX + jbase;
  short* kl0 = &Kt[(sr * 8 + (sc0 ^ (sr & 7))) * 8];
  short* kl1 = &Kt[(sr * 8 + (sc1 ^ (sr & 7))) * 8];
  short* vl0 = &Vtl[(sr * 8 + (sc0 ^ (sr & 7))) * 8];
  short* vl1 = &Vtl[(sr * 8 + (sc1 ^ (sr & 7))) * 8];

  v4f o[4];
  float lsum[4];
  for (int t = 0; t < 4; ++t) o[t] = (v4f){0.f, 0.f, 0.f, 0.f};
  for (int r = 0; r < 4; ++r) lsum[r] = 0.f;

  v8s pk0 = ldbf8(kg + sc0 * 8), pk1 = ldbf8(kg + sc1 * 8);
  v8s pv0 = ldbf8(vg + sc0 * 8), pv1 = ldbf8(vg + sc1 * 8);

  for (int j0 = 0; j0 < NCTX / 4; j0 += 64) {
    __syncthreads();                       // prev iter's tile reads done
    *(v8s*)kl0 = pk0; *(v8s*)kl1 = pk1;
    *(v8s*)vl0 = pv0; *(v8s*)vl1 = pv1;
    __syncthreads();                       // tiles visible
    int jn = j0 + 64;
    if (jn < NCTX / 4) {
      pk0 = ldbf8(kg + jn * kstride + sc0 * 8);
      pk1 = ldbf8(kg + jn * kstride + sc1 * 8);
      pv0 = ldbf8(vg + jn + sc0 * 8);
      pv1 = ldbf8(vg + jn + sc1 * 8);
    }
    v4f s[4];
#pragma unroll
    for (int kt = 0; kt < 4; ++kt) {
      int R = kt * 16 + l16;
      v8s kb0 = *(const v8s*)&Kt[(R * 8 + (quad ^ (R & 7))) * 8];
      v8s kb1 = *(const v8s*)&Kt[(R * 8 + ((quad + 4) ^ (R & 7))) * 8];
      v4f t0 = (v4f){0.f, 0.f, 0.f, 0.f};
      t0 = MFMA(aq0, kb0, t0);
      s[kt] = MFMA(aq1, kb1, t0);
    }
    short* pw = &P[wave][0];
#pragma unroll
    for (int kt = 0; kt < 4; ++kt)
      for (int r = 0; r < 4; ++r) {
        float p = exp2f(fminf(s[kt][r], 40.f));   // K pre-scaled by log2e/sqrt(512)
        lsum[r] += p;
        pw[(quad * 4 + r) * 72 + kt * 16 + l16] = f2bf(p);
      }
    // P is wave-private: wave-local LDS ordering is enough (no block barrier)
    asm volatile("s_waitcnt lgkmcnt(0)" ::: "memory");
    v8s pa0 = *(const v8s*)&pw[l16 * 72 + quad * 8];
    v8s pa1 = *(const v8s*)&pw[l16 * 72 + 32 + quad * 8];
#pragma unroll
    for (int t = 0; t < 4; ++t) {
      int R = t * 16 + l16;
      v8s bv0 = *(const v8s*)&Vtl[(R * 8 + (quad ^ (R & 7))) * 8];
      v8s bv1 = *(const v8s*)&Vtl[(R * 8 + ((quad + 4) ^ (R & 7))) * 8];
      o[t] = MFMA(pa0, bv0, o[t]);
      o[t] = MFMA(pa1, bv1, o[t]);
    }
  }
  for (int r = 0; r < 4; ++r) {
    lsum[r] += __shfl_xor(lsum[r], 1);
    lsum[r] += __shfl_xor(lsum[r], 2);
    lsum[r] += __shfl_xor(lsum[r], 4);
    lsum[r] += __shfl_xor(lsum[r], 8);
  }
  // ---- write fp32 partials (release) ----
  float* ob = opart + (size_t)z * (NCTX * HID);
  for (int t = 0; t < 4; ++t)
    for (int r = 0; r < 4; ++r)
      ob[(i0 + quad * 4 + r) * HID + D0 + t * 16 + l16] = o[t][r];
  if (l16 == 0)
    for (int r = 0; r < 4; ++r)
      lspart[z * (8 * NCTX) + h * NCTX + i0 + quad * 4 + r] = lsum[r];

  __threadfence();                          // release partials device-wide
  __syncthreads();                          // all threads' stores fenced
  if (tid == 0) arrival = atomicAdd(&cnt[blockIdx.y * gridDim.x + blockIdx.x], 1);
  __syncthreads();
  if (arrival != 3) return;                 // not the last z-chunk
  __threadfence();                          // acquire other blocks' partials

  // ---- last block: combine all 4 z-chunks (fixed z-order) and write out ----
  float dtot[4];
#pragma unroll
  for (int r = 0; r < 4; ++r) {
    float d = 0.f;
    for (int zz = 0; zz < 4; ++zz)
      d += (zz == z) ? lsum[r]
                     : lspart[zz * (8 * NCTX) + h * NCTX + i0 + quad * 4 + r];
    dtot[r] = d;
  }
#pragma unroll
  for (int t = 0; t < 4; ++t)
    for (int r = 0; r < 4; ++r) {
      int grow = i0 + quad * 4 + r;
      int gcol = D0 + t * 16 + l16;
      float osum = 0.f;
      for (int zz = 0; zz < 4; ++zz)
        osum += (zz == z) ? o[t][r]
                          : opart[(size_t)zz * (NCTX * HID) + grow * HID + gcol];
      oout[grow * HID + gcol] = f2bf(bf2f(Q[grow * qstride + gcol]) + osum / dtot[r]);
    }
}

// ---------------- final fc: out[j] = P[j,:] . fc_w + fc_b --------------------
__global__ __launch_bounds__(64) void k_fc(const short* __restrict__ P,
                                           const float* __restrict__ fcw,
                                           const float* __restrict__ fcb,
                                           float* __restrict__ out) {
  int j = blockIdx.x, l = threadIdx.x;
  float s = 0.f;
  int d0 = l * 8;
  for (int d = d0; d < d0 + 8; ++d) s += bf2f(P[j * HID + d]) * fcw[d];
  for (int msk = 1; msk < 64; msk <<= 1) s += __shfl_xor(s, msk);
  if (l == 0) out[j] = s + fcb[0];
}

// =============================================================================
extern "C" void kernel_launch(void* const* d_in, const int* in_sizes, int n_in,
                              void* d_out, int out_size, void* d_ws, size_t ws_size,
                              hipStream_t stream) {
  const int* is_cat = (const int*)d_in[0];
  const int* cat_idx = (const int*)d_in[1];
  const int* reg_idx = (const int*)d_in[2];
  const float* reg_values = (const float*)d_in[3];
  const float* cat_table = (const float*)d_in[4];
  const float* reg_table = (const float*)d_in[5];
  const float* reg_W = (const float*)d_in[6];
  const float* reg_b = (const float*)d_in[7];
  const float* q0_w = (const float*)d_in[8];  const float* q0_b = (const float*)d_in[9];
  const float* k0_w = (const float*)d_in[10]; const float* k0_b = (const float*)d_in[11];
  const float* v0_w = (const float*)d_in[12]; const float* v0_b = (const float*)d_in[13];
  const float* o0_w = (const float*)d_in[14]; const float* o0_b = (const float*)d_in[15];
  const float* qs_w = (const float*)d_in[16]; const float* qs_b = (const float*)d_in[17];
  const float* ks_w = (const float*)d_in[18]; const float* ks_b = (const float*)d_in[19];
  const float* vs_w = (const float*)d_in[20]; const float* vs_b = (const float*)d_in[21];
  const float* os_w = (const float*)d_in[22]; const float* os_b = (const float*)d_in[23];
  const float* S    = (const float*)d_in[24];
  const float* pq_w = (const float*)d_in[25]; const float* pq_b = (const float*)d_in[26];
  const float* pk_w = (const float*)d_in[27]; const float* pk_b = (const float*)d_in[28];
  const float* pv_w = (const float*)d_in[29]; const float* pv_b = (const float*)d_in[30];
  const float* po_w = (const float*)d_in[31]; const float* po_b = (const float*)d_in[32];
  const float* fc_w = (const float*)d_in[33]; const float* fc_b = (const float*)d_in[34];

  short* W = (short*)d_ws;

  // ---- packed bf16 weights (shorts). Per layer: [wq;wk] adjacent, wv, wo.
  const unsigned OWQK[4] = {0u, 1441792u, 2490368u, 3538944u};
  const unsigned OWV[4]  = {786432u, 1966080u, 3014656u, 4063232u};
  const unsigned OWO[4]  = {1179648u, 2228224u, 3276800u, 4325376u};
  const unsigned OPQW = 4587520u, OPKW = 4849664u, OPVW = 5111808u, OPOW = 5373952u;
  const unsigned TOTW = 5636096u;
  // ---- bf16 activations
  const unsigned OEMB = TOTW;              // 2048x768
  const unsigned OXA  = OEMB + 1572864u;   // 2048x512
  const unsigned OXB  = OXA + 1048576u;    // 2048x512
  const unsigned OQK  = OXB + 1048576u;    // 2048x1024 (Q|K fused; K pre-scaled)
  const unsigned OVT  = OQK + 2097152u;    // 512x2048 (V transposed)
  const unsigned OOH  = OVT + 1048576u;    // 2048x512 (attn out)
  const unsigned OSB  = OOH + 1048576u;    // 64x512 (S padded)
  const unsigned OQPP = OSB + 32768u;      // 64x512
  const unsigned OKPP = OQPP + 32768u;     // 2048x512
  const unsigned OOHP = OKPP + 1048576u;   // 64x512
  const unsigned OPP  = OOHP + 32768u;     // 32x512 (PMA final, padded)
  const unsigned OF32 = OPP + 32768u;      // fp32 region starts here (even)
  float* F = (float*)(W + OF32);           // opart: 4 x [2048x512] fp32
  float* LS = F + 4u * 1048576u;           // lspart: 4 x [8x2048] fp32
  int* CNT = (int*)(LS + 4u * 8u * NCTX);  // 5 x 256 split-K arrival counters

  const float C2 = 0.06375872f;            // log2(e)/sqrt(512), folded into K

  // ---- fused prep: weight conversion + embedding + S build + counters ----
  ConvDesc cd;
  const float* srcs[20] = {
      q0_w, k0_w, v0_w, o0_w,
      qs_w, ks_w, vs_w, os_w,
      qs_w + 262144, ks_w + 262144, vs_w + 262144, os_w + 262144,
      qs_w + 524288, ks_w + 524288, vs_w + 524288, os_w + 524288,
      pq_w, pk_w, pv_w, po_w};
  const unsigned cums[21] = {0u,       393216u,  786432u,  1179648u, 1441792u,
                             1703936u, 1966080u, 2228224u, 2490368u, 2752512u,
                             3014656u, 3276800u, 3538944u, 3801088u, 4063232u,
                             4325376u, 4587520u, 4849664u, 5111808u, 5373952u,
                             5636096u};
  for (int i = 0; i < 20; ++i) cd.src[i] = srcs[i];
  for (int i = 0; i < 21; ++i) cd.cum[i] = cums[i];
  k_prep<<<NB_CONV + NB_EMB + NB_S + 1, 256, 0, stream>>>(
      cd, W, is_cat, cat_idx, reg_idx, reg_values, cat_table, reg_table,
      reg_W, reg_b, W + OEMB, S, W + OSB, CNT);

  const float* bq[4] = {q0_b, qs_b, qs_b + 512, qs_b + 1024};
  const float* bk[4] = {k0_b, ks_b, ks_b + 512, ks_b + 1024};
  const float* bv[4] = {v0_b, vs_b, vs_b + 512, vs_b + 1024};
  const float* bo[4] = {o0_b, os_b, os_b + 512, os_b + 1024};
  const unsigned oxin[4]  = {OEMB, OXA, OXB, OXA};
  const unsigned oxout[4] = {OXA, OXB, OXA, OXB};

  dim3 gf(32, 8, 4);  // flash: 32 q-blocks x 8 heads x 4 key-chunks

  for (int l = 0; l < 4; ++l) {
    const short* X = W + oxin[l];
    short* Xout = W + oxout[l];
    int KKl = (l == 0) ? 768 : 512;
    // fused QK-projection (K scaled by C2) + V^T production: one launch
    GemmBatch gb{};
    gb.nj = 2;
    gb.j[0] = {X, W + OWQK[l], bq[l], bk[l], W + OQK, 1024, KKl, 0, 16, 0, 1.f, C2};
    gb.j[1] = {W + OWV[l], X, bv[l], nullptr, W + OVT, 2048, KKl, 1, 32, 1024, 1.f, 1.f};
    k_gemm_multi<<<1536, 64, 0, stream>>>(gb);
    k_flash<<<gf, 256, 0, stream>>>(W + OQK, 1024, W + OQK + 512, 1024, W + OVT,
                                    F, LS, CNT + l * 256, W + OOH);
    k_gemm_ff<512><<<dim3(8, 64), 64, 0, stream>>>(W + OOH, W + OWO[l], bo[l], W + OOH, Xout, 512);
  }

  // ---- PMA decoder ----
  // fused pq + pk (scaled by C2) + pv projections: one launch
  GemmBatch gp{};
  gp.nj = 3;
  gp.j[0] = {W + OSB, W + OPQW, pq_b, pq_b, W + OQPP, 512, 512, 0, 8, 0, 1.f, 1.f};
  gp.j[1] = {W + OXB, W + OPKW, pk_b, pk_b, W + OKPP, 512, 512, 0, 8, 16, C2, C2};
  gp.j[2] = {W + OPVW, W + OXB, pv_b, nullptr, W + OVT, 2048, 512, 1, 32, 528, 1.f, 1.f};
  k_gemm_multi<<<1040, 64, 0, stream>>>(gp);
  // grid (1,8,4): q rows 0..63; rows beyond 7 are bias-only/garbage-finite,
  // combine tail writes all 64 rows of OOHP but only rows 0..6 reach d_out.
  k_flash<<<dim3(1, 8, 4), 256, 0, stream>>>(W + OQPP, 512, W + OKPP, 512, W + OVT,
                                             F, LS, CNT + 4 * 256, W + OOHP);
  k_gemm_ff<512><<<dim3(8, 1), 64, 0, stream>>>(W + OOHP, W + OPOW, po_b, W + OOHP, W + OPP, 512);
  k_fc<<<7, 64, 0, stream>>>(W + OPP, fc_w, fc_b, (float*)d_out);
}

// Round 5
// 736.664 us; speedup vs baseline: 1.7414x; 1.7414x over previous
//
#include <hip/hip_runtime.h>
#include <hip/hip_bf16.h>
#include <stdint.h>

// Set Transformer forward on gfx950. Round 8.
// R7 regression (+553us) root-caused: __threadfence() in flash = agent-scope
// fence = buffer_wbl2 + buffer_inv (full 4MiB L2 writeback+invalidate per
// XCD, thousands of times). RULE: no device-scope fences in hot paths on
// multi-XCD CDNA; launch boundaries provide coherence for free.
// R8 = revert to R4 structure (best measured 728.0: plain flash + separate
// k_combine, GEMM unroll 4) + PMA tail fused into ONE single-block kernel
// (combine -> LDS -> po-proj GEMM -> fc), block-local barriers only.
// 22 -> 20 dispatches, bit-identical arithmetic.

#define HID 512
#define EMBD 768
#define NCTX 2048
#define HD 64

typedef __attribute__((ext_vector_type(8))) short v8s;   // 8 x bf16
typedef __attribute__((ext_vector_type(4))) float v4f;   // MFMA accumulator

#define MFMA(a, b, c) __builtin_amdgcn_mfma_f32_16x16x32_bf16((a), (b), (c), 0, 0, 0)

__device__ __forceinline__ short f2bf(float f) {
  return __builtin_bit_cast(short, __float2bfloat16(f));
}
__device__ __forceinline__ float bf2f(short s) {
  uint32_t u = ((uint32_t)(uint16_t)s) << 16;
  return __builtin_bit_cast(float, u);
}
__device__ __forceinline__ v8s ldbf8(const short* p) { return *(const v8s*)p; }

// ---------------- fused prep: weight convert + embedding + S build ----------
struct ConvDesc {
  const float* src[20];
  unsigned cum[21];
};

#define NB_CONV 22016u   // 5636096 / 256
#define NB_EMB 6144u     // 2048*768 / 256
#define NB_S 128u        // 64*512 / 256

__global__ __launch_bounds__(256) void k_prep(
    ConvDesc d, short* __restrict__ Wdst,
    const int* __restrict__ is_cat, const int* __restrict__ cat_idx,
    const int* __restrict__ reg_idx, const float* __restrict__ reg_values,
    const float* __restrict__ cat_table, const float* __restrict__ reg_table,
    const float* __restrict__ reg_W, const float* __restrict__ reg_b,
    short* __restrict__ emb_out, const float* __restrict__ S,
    short* __restrict__ s_out) {
  unsigned b = blockIdx.x;
  if (b < NB_CONV) {
    unsigned i = b * 256u + threadIdx.x;
    if (i >= d.cum[20]) return;
    int t = 0;
    while (i >= d.cum[t + 1]) ++t;
    Wdst[i] = f2bf(d.src[t][i - d.cum[t]]);
  } else if (b < NB_CONV + NB_EMB) {
    int i = (int)(b - NB_CONV) * 256 + threadIdx.x;
    int n = i / EMBD, e = i - n * EMBD;
    float v;
    if (is_cat[n]) {
      v = cat_table[(long)cat_idx[n] * EMBD + e];
    } else {
      int r = reg_idx[n];
      if (e < 512) v = reg_table[r * 512 + e];
      else {
        int e2 = e - 512;
        v = reg_W[r * 256 + e2] * reg_values[n] + reg_b[r * 256 + e2];
      }
    }
    emb_out[i] = f2bf(v);
  } else {
    int i = (int)(b - NB_CONV - NB_EMB) * 256 + threadIdx.x;
    int row = i >> 9;
    s_out[i] = (row < 7) ? f2bf(S[i]) : (short)0;
  }
}

// ---------------- multi-job NT GEMM: C[M,N] = A[M,K] @ B[N,K]^T -------------
// Up to 3 independent GEMMs in one launch; blocks decode their job from a
// base offset. One wave per 32x64 tile.
// epi 0: out = (acc + (col<512 ? biasA[col] : biasB[col-512])) * (col<512?sA:sB)
// epi 1: out = acc + biasA[row]
struct GemmJob {
  const short* A;
  const short* B;
  const float* biasA;
  const float* biasB;
  short* out;
  int N, KK, epi, gx, base;
  float sA, sB;
};
struct GemmBatch {
  GemmJob j[3];
  int nj;
};

__global__ __launch_bounds__(64) void k_gemm_multi(GemmBatch gb) {
  int wg = blockIdx.x;
  int ji = 0;
  if (gb.nj > 1 && wg >= gb.j[1].base) ji = 1;
  if (gb.nj > 2 && wg >= gb.j[2].base) ji = 2;
  const GemmJob& j = gb.j[ji];
  int rel = wg - j.base;
  int bx = rel % j.gx, by = rel / j.gx;
  int l = threadIdx.x, l16 = l & 15, quad = l >> 4;
  int i0 = by * 32, n0 = bx * 64;
  const int KK = j.KK;
  const short* a0p = j.A + (i0 + l16) * KK + quad * 8;
  const short* a1p = a0p + 16 * KK;
  const short* bp = j.B + (n0 + l16) * KK + quad * 8;
  v4f acc[2][4];
  for (int g = 0; g < 2; ++g)
    for (int t = 0; t < 4; ++t) acc[g][t] = (v4f){0.f, 0.f, 0.f, 0.f};
#pragma unroll 4
  for (int k = 0; k < KK; k += 32) {
    v8s a0 = ldbf8(a0p + k);
    v8s a1 = ldbf8(a1p + k);
#pragma unroll
    for (int t = 0; t < 4; ++t) {
      v8s b = ldbf8(bp + t * 16 * KK + k);
      acc[0][t] = MFMA(a0, b, acc[0][t]);
      acc[1][t] = MFMA(a1, b, acc[1][t]);
    }
  }
  for (int g = 0; g < 2; ++g)
    for (int t = 0; t < 4; ++t) {
      int col = n0 + t * 16 + l16;
      float bc = 0.f, sc = 1.f;
      if (j.epi == 0) {
        bc = (col < 512) ? j.biasA[col] : j.biasB[col - 512];
        sc = (col < 512) ? j.sA : j.sB;
      }
      for (int r = 0; r < 4; ++r) {
        int row = i0 + g * 16 + quad * 4 + r;
        float v = acc[g][t][r];
        v = (j.epi == 0) ? (v + bc) * sc : v + j.biasA[row];
        j.out[row * j.N + col] = f2bf(v);
      }
    }
}

// ---------------- single-job GEMM with residual+relu epilogue (O-proj) ------
// out = resid + relu(acc + biasA[col])
template <int KK>
__global__ __launch_bounds__(64) void k_gemm_ff(const short* __restrict__ A,
                                               const short* __restrict__ B,
                                               const float* __restrict__ biasA,
                                               const short* __restrict__ resid,
                                               short* __restrict__ out, int N) {
  int l = threadIdx.x, l16 = l & 15, quad = l >> 4;
  int i0 = blockIdx.y * 32, n0 = blockIdx.x * 64;
  const short* a0p = A + (i0 + l16) * KK + quad * 8;
  const short* a1p = a0p + 16 * KK;
  const short* bp = B + (n0 + l16) * KK + quad * 8;
  v4f acc[2][4];
  for (int g = 0; g < 2; ++g)
    for (int t = 0; t < 4; ++t) acc[g][t] = (v4f){0.f, 0.f, 0.f, 0.f};
#pragma unroll 4
  for (int k = 0; k < KK; k += 32) {
    v8s a0 = ldbf8(a0p + k);
    v8s a1 = ldbf8(a1p + k);
#pragma unroll
    for (int t = 0; t < 4; ++t) {
      v8s b = ldbf8(bp + t * 16 * KK + k);
      acc[0][t] = MFMA(a0, b, acc[0][t]);
      acc[1][t] = MFMA(a1, b, acc[1][t]);
    }
  }
  for (int g = 0; g < 2; ++g)
    for (int t = 0; t < 4; ++t) {
      int col = n0 + t * 16 + l16;
      float bc = biasA[col];
      for (int r = 0; r < 4; ++r) {
        int row = i0 + g * 16 + quad * 4 + r;
        float v = bf2f(resid[row * N + col]) + fmaxf(acc[g][t][r] + bc, 0.f);
        out[row * N + col] = f2bf(v);
      }
    }
}

// ---------------- flash attention, split-K=4, 4 waves/block ------------------
// Block: 256 thr = 4 waves, each wave a 16-query tile; z = key-chunk of 512.
// K is pre-scaled by log2(e)/sqrt(512) in its projection epilogue, so QK^T
// feeds exp2 directly. Writes UNNORMALIZED fp32 partial O and per-row
// partial denominators.
__global__ __launch_bounds__(256) void k_flash(const short* __restrict__ Q, int qstride,
                                               const short* __restrict__ Kp, int kstride,
                                               const short* __restrict__ Vt,
                                               float* __restrict__ opart,
                                               float* __restrict__ lspart) {
  __shared__ __align__(16) short Kt[64 * 64];   // XOR-swizzled 16B chunks
  __shared__ __align__(16) short Vtl[64 * 64];
  __shared__ __align__(16) short P[4][16 * 72];
  const int tid = threadIdx.x;
  const int wave = tid >> 6, l = tid & 63, l16 = l & 15, quad = l >> 4;
  const int h = blockIdx.y, D0 = h * HD;
  const int i0 = blockIdx.x * 64 + wave * 16;
  const int z = blockIdx.z, jbase = z * (NCTX / 4);

  const short* qrow = Q + (i0 + l16) * qstride + D0 + quad * 8;
  const v8s aq0 = ldbf8(qrow);
  const v8s aq1 = ldbf8(qrow + 32);

  const int sr = tid >> 2, sc0 = tid & 3, sc1 = sc0 + 4;
  const short* kg = Kp + (jbase + sr) * kstride + D0;
  const short* vg = Vt + (D0 + sr) * NCTX + jbase;
  short* kl0 = &Kt[(sr * 8 + (sc0 ^ (sr & 7))) * 8];
  short* kl1 = &Kt[(sr * 8 + (sc1 ^ (sr & 7))) * 8];
  short* vl0 = &Vtl[(sr * 8 + (sc0 ^ (sr & 7))) * 8];
  short* vl1 = &Vtl[(sr * 8 + (sc1 ^ (sr & 7))) * 8];

  v4f o[4];
  float lsum[4];
  for (int t = 0; t < 4; ++t) o[t] = (v4f){0.f, 0.f, 0.f, 0.f};
  for (int r = 0; r < 4; ++r) lsum[r] = 0.f;

  v8s pk0 = ldbf8(kg + sc0 * 8), pk1 = ldbf8(kg + sc1 * 8);
  v8s pv0 = ldbf8(vg + sc0 * 8), pv1 = ldbf8(vg + sc1 * 8);

  for (int j0 = 0; j0 < NCTX / 4; j0 += 64) {
    __syncthreads();                       // prev iter's tile reads done
    *(v8s*)kl0 = pk0; *(v8s*)kl1 = pk1;
    *(v8s*)vl0 = pv0; *(v8s*)vl1 = pv1;
    __syncthreads();                       // tiles visible
    int jn = j0 + 64;
    if (jn < NCTX / 4) {
      pk0 = ldbf8(kg + jn * kstride + sc0 * 8);
      pk1 = ldbf8(kg + jn * kstride + sc1 * 8);
      pv0 = ldbf8(vg + jn + sc0 * 8);
      pv1 = ldbf8(vg + jn + sc1 * 8);
    }
    v4f s[4];
#pragma unroll
    for (int kt = 0; kt < 4; ++kt) {
      int R = kt * 16 + l16;
      v8s kb0 = *(const v8s*)&Kt[(R * 8 + (quad ^ (R & 7))) * 8];
      v8s kb1 = *(const v8s*)&Kt[(R * 8 + ((quad + 4) ^ (R & 7))) * 8];
      v4f t0 = (v4f){0.f, 0.f, 0.f, 0.f};
      t0 = MFMA(aq0, kb0, t0);
      s[kt] = MFMA(aq1, kb1, t0);
    }
    short* pw = &P[wave][0];
#pragma unroll
    for (int kt = 0; kt < 4; ++kt)
      for (int r = 0; r < 4; ++r) {
        float p = exp2f(fminf(s[kt][r], 40.f));   // K pre-scaled by log2e/sqrt(512)
        lsum[r] += p;
        pw[(quad * 4 + r) * 72 + kt * 16 + l16] = f2bf(p);
      }
    // P is wave-private: wave-local LDS ordering is enough (no block barrier)
    asm volatile("s_waitcnt lgkmcnt(0)" ::: "memory");
    v8s pa0 = *(const v8s*)&pw[l16 * 72 + quad * 8];
    v8s pa1 = *(const v8s*)&pw[l16 * 72 + 32 + quad * 8];
#pragma unroll
    for (int t = 0; t < 4; ++t) {
      int R = t * 16 + l16;
      v8s bv0 = *(const v8s*)&Vtl[(R * 8 + (quad ^ (R & 7))) * 8];
      v8s bv1 = *(const v8s*)&Vtl[(R * 8 + ((quad + 4) ^ (R & 7))) * 8];
      o[t] = MFMA(pa0, bv0, o[t]);
      o[t] = MFMA(pa1, bv1, o[t]);
    }
  }
  for (int r = 0; r < 4; ++r) {
    lsum[r] += __shfl_xor(lsum[r], 1);
    lsum[r] += __shfl_xor(lsum[r], 2);
    lsum[r] += __shfl_xor(lsum[r], 4);
    lsum[r] += __shfl_xor(lsum[r], 8);
  }
  float* ob = opart + (size_t)z * (NCTX * HID);
  for (int t = 0; t < 4; ++t)
    for (int r = 0; r < 4; ++r)
      ob[(i0 + quad * 4 + r) * HID + D0 + t * 16 + l16] = o[t][r];
  if (l16 == 0)
    for (int r = 0; r < 4; ++r)
      lspart[z * (8 * NCTX) + h * NCTX + i0 + quad * 4 + r] = lsum[r];
}

// ---------------- combine partials: out = bf16(Qresid + (sum O_p)/(sum l_p)) --
__global__ void k_combine(const float* __restrict__ op, const float* __restrict__ ls,
                          const short* __restrict__ Qr, int qstride,
                          short* __restrict__ out) {
  const int PS = NCTX * HID;
  int i = blockIdx.x * 256 + threadIdx.x;  // M*512 threads
  int row = i >> 9, col = i & 511, h = col >> 6;
  float o = op[i] + op[i + PS] + op[i + 2 * PS] + op[i + 3 * PS];
  int li = h * NCTX + row;
  float d = ls[li] + ls[li + 8 * NCTX] + ls[li + 16 * NCTX] + ls[li + 24 * NCTX];
  out[i] = f2bf(bf2f(Qr[row * qstride + col]) + o / d);
}

// ---------------- fused PMA tail: combine + po-proj(+relu+resid) + fc --------
// One block, 512 threads (8 waves). All intermediates in LDS; block-local
// barriers only (no device-scope sync -- R7 lesson). Arithmetic is op-for-op
// identical to the separate k_combine / k_gemm_ff / k_fc path.
__global__ __launch_bounds__(512) void k_pma_tail(
    const float* __restrict__ op, const float* __restrict__ ls,
    const short* __restrict__ Qr,           // OQPP, stride 512
    const short* __restrict__ Bw,           // po weights bf16 [512][512] (NT)
    const float* __restrict__ bo,           // po bias
    const float* __restrict__ fcw, const float* __restrict__ fcb,
    float* __restrict__ out) {
  __shared__ __align__(16) short ooh[16][520];  // +8 pad: 2-way banks (free)
  __shared__ __align__(16) short pp[16][520];
  const int tid = threadIdx.x;
  const int PS = NCTX * HID;
  // phase 1: split-K combine, 16 rows x 512 cols (bit-identical to k_combine)
  {
    int col = tid;  // 512 threads, one column each
    int h = col >> 6;
    for (int row = 0; row < 16; ++row) {
      int i = row * 512 + col;
      float o = op[i] + op[i + PS] + op[i + 2 * PS] + op[i + 3 * PS];
      int li = h * NCTX + row;
      float d = ls[li] + ls[li + 8 * NCTX] + ls[li + 16 * NCTX] + ls[li + 24 * NCTX];
      ooh[row][col] = f2bf(bf2f(Qr[row * 512 + col]) + o / d);
    }
  }
  __syncthreads();
  // phase 2: ff gemm rows 0..15; wave w owns cols [w*64, w*64+64)
  const int w = tid >> 6, l = tid & 63, l16 = l & 15, quad = l >> 4;
  {
    int n0 = w * 64;
    v4f acc[4];
    for (int t = 0; t < 4; ++t) acc[t] = (v4f){0.f, 0.f, 0.f, 0.f};
    const short* bp = Bw + (n0 + l16) * 512 + quad * 8;
#pragma unroll 4
    for (int k = 0; k < 512; k += 32) {
      v8s a0 = *(const v8s*)&ooh[l16][k + quad * 8];
#pragma unroll
      for (int t = 0; t < 4; ++t) {
        v8s b = ldbf8(bp + t * 16 * 512 + k);
        acc[t] = MFMA(a0, b, acc[t]);
      }
    }
    for (int t = 0; t < 4; ++t) {
      int col = n0 + t * 16 + l16;
      float bc = bo[col];
      for (int r = 0; r < 4; ++r) {
        int row = quad * 4 + r;
        float v = bf2f(ooh[row][col]) + fmaxf(acc[t][r] + bc, 0.f);
        pp[row][col] = f2bf(v);
      }
    }
  }
  __syncthreads();
  // phase 3: fc -- wave w computes output row w (w < 7)
  if (w < 7) {
    float s = 0.f;
    int d0 = l * 8;
    for (int d = d0; d < d0 + 8; ++d) s += bf2f(pp[w][d]) * fcw[d];
    for (int msk = 1; msk < 64; msk <<= 1) s += __shfl_xor(s, msk);
    if (l == 0) out[w] = s + fcb[0];
  }
}

// =============================================================================
extern "C" void kernel_launch(void* const* d_in, const int* in_sizes, int n_in,
                              void* d_out, int out_size, void* d_ws, size_t ws_size,
                              hipStream_t stream) {
  const int* is_cat = (const int*)d_in[0];
  const int* cat_idx = (const int*)d_in[1];
  const int* reg_idx = (const int*)d_in[2];
  const float* reg_values = (const float*)d_in[3];
  const float* cat_table = (const float*)d_in[4];
  const float* reg_table = (const float*)d_in[5];
  const float* reg_W = (const float*)d_in[6];
  const float* reg_b = (const float*)d_in[7];
  const float* q0_w = (const float*)d_in[8];  const float* q0_b = (const float*)d_in[9];
  const float* k0_w = (const float*)d_in[10]; const float* k0_b = (const float*)d_in[11];
  const float* v0_w = (const float*)d_in[12]; const float* v0_b = (const float*)d_in[13];
  const float* o0_w = (const float*)d_in[14]; const float* o0_b = (const float*)d_in[15];
  const float* qs_w = (const float*)d_in[16]; const float* qs_b = (const float*)d_in[17];
  const float* ks_w = (const float*)d_in[18]; const float* ks_b = (const float*)d_in[19];
  const float* vs_w = (const float*)d_in[20]; const float* vs_b = (const float*)d_in[21];
  const float* os_w = (const float*)d_in[22]; const float* os_b = (const float*)d_in[23];
  const float* S    = (const float*)d_in[24];
  const float* pq_w = (const float*)d_in[25]; const float* pq_b = (const float*)d_in[26];
  const float* pk_w = (const float*)d_in[27]; const float* pk_b = (const float*)d_in[28];
  const float* pv_w = (const float*)d_in[29]; const float* pv_b = (const float*)d_in[30];
  const float* po_w = (const float*)d_in[31]; const float* po_b = (const float*)d_in[32];
  const float* fc_w = (const float*)d_in[33]; const float* fc_b = (const float*)d_in[34];

  short* W = (short*)d_ws;

  // ---- packed bf16 weights (shorts). Per layer: [wq;wk] adjacent, wv, wo.
  const unsigned OWQK[4] = {0u, 1441792u, 2490368u, 3538944u};
  const unsigned OWV[4]  = {786432u, 1966080u, 3014656u, 4063232u};
  const unsigned OWO[4]  = {1179648u, 2228224u, 3276800u, 4325376u};
  const unsigned OPQW = 4587520u, OPKW = 4849664u, OPVW = 5111808u, OPOW = 5373952u;
  const unsigned TOTW = 5636096u;
  // ---- bf16 activations
  const unsigned OEMB = TOTW;              // 2048x768
  const unsigned OXA  = OEMB + 1572864u;   // 2048x512
  const unsigned OXB  = OXA + 1048576u;    // 2048x512
  const unsigned OQK  = OXB + 1048576u;    // 2048x1024 (Q|K fused; K pre-scaled)
  const unsigned OVT  = OQK + 2097152u;    // 512x2048 (V transposed)
  const unsigned OOH  = OVT + 1048576u;    // 2048x512 (attn out)
  const unsigned OSB  = OOH + 1048576u;    // 64x512 (S padded)
  const unsigned OQPP = OSB + 32768u;      // 64x512
  const unsigned OKPP = OQPP + 32768u;     // 2048x512
  const unsigned OOHP = OKPP + 1048576u;   // 64x512 (unused in R8 tail path)
  const unsigned OPP  = OOHP + 32768u;     // 32x512 (unused in R8 tail path)
  const unsigned OF32 = OPP + 32768u;      // fp32 region starts here (even)
  float* F = (float*)(W + OF32);           // opart: 4 x [2048x512] fp32
  float* LS = F + 4u * 1048576u;           // lspart: 4 x [8x2048] fp32

  const float C2 = 0.06375872f;            // log2(e)/sqrt(512), folded into K

  // ---- fused prep: weight conversion + embedding + S build ----
  ConvDesc cd;
  const float* srcs[20] = {
      q0_w, k0_w, v0_w, o0_w,
      qs_w, ks_w, vs_w, os_w,
      qs_w + 262144, ks_w + 262144, vs_w + 262144, os_w + 262144,
      qs_w + 524288, ks_w + 524288, vs_w + 524288, os_w + 524288,
      pq_w, pk_w, pv_w, po_w};
  const unsigned cums[21] = {0u,       393216u,  786432u,  1179648u, 1441792u,
                             1703936u, 1966080u, 2228224u, 2490368u, 2752512u,
                             3014656u, 3276800u, 3538944u, 3801088u, 4063232u,
                             4325376u, 4587520u, 4849664u, 5111808u, 5373952u,
                             5636096u};
  for (int i = 0; i < 20; ++i) cd.src[i] = srcs[i];
  for (int i = 0; i < 21; ++i) cd.cum[i] = cums[i];
  k_prep<<<NB_CONV + NB_EMB + NB_S, 256, 0, stream>>>(
      cd, W, is_cat, cat_idx, reg_idx, reg_values, cat_table, reg_table,
      reg_W, reg_b, W + OEMB, S, W + OSB);

  const float* bq[4] = {q0_b, qs_b, qs_b + 512, qs_b + 1024};
  const float* bk[4] = {k0_b, ks_b, ks_b + 512, ks_b + 1024};
  const float* bv[4] = {v0_b, vs_b, vs_b + 512, vs_b + 1024};
  const float* bo[4] = {o0_b, os_b, os_b + 512, os_b + 1024};
  const unsigned oxin[4]  = {OEMB, OXA, OXB, OXA};
  const unsigned oxout[4] = {OXA, OXB, OXA, OXB};

  dim3 gf(32, 8, 4);  // flash: 32 q-blocks x 8 heads x 4 key-chunks

  for (int l = 0; l < 4; ++l) {
    const short* X = W + oxin[l];
    short* Xout = W + oxout[l];
    int KKl = (l == 0) ? 768 : 512;
    // fused QK-projection (K scaled by C2) + V^T production: one launch
    GemmBatch gb{};
    gb.nj = 2;
    gb.j[0] = {X, W + OWQK[l], bq[l], bk[l], W + OQK, 1024, KKl, 0, 16, 0, 1.f, C2};
    gb.j[1] = {W + OWV[l], X, bv[l], nullptr, W + OVT, 2048, KKl, 1, 32, 1024, 1.f, 1.f};
    k_gemm_multi<<<1536, 64, 0, stream>>>(gb);
    k_flash<<<gf, 256, 0, stream>>>(W + OQK, 1024, W + OQK + 512, 1024, W + OVT, F, LS);
    k_combine<<<(2048 * 512) / 256, 256, 0, stream>>>(F, LS, W + OQK, 1024, W + OOH);
    k_gemm_ff<512><<<dim3(8, 64), 64, 0, stream>>>(W + OOH, W + OWO[l], bo[l], W + OOH, Xout, 512);
  }

  // ---- PMA decoder ----
  // fused pq + pk (scaled by C2) + pv projections: one launch
  GemmBatch gp{};
  gp.nj = 3;
  gp.j[0] = {W + OSB, W + OPQW, pq_b, pq_b, W + OQPP, 512, 512, 0, 8, 0, 1.f, 1.f};
  gp.j[1] = {W + OXB, W + OPKW, pk_b, pk_b, W + OKPP, 512, 512, 0, 8, 16, C2, C2};
  gp.j[2] = {W + OPVW, W + OXB, pv_b, nullptr, W + OVT, 2048, 512, 1, 32, 528, 1.f, 1.f};
  k_gemm_multi<<<1040, 64, 0, stream>>>(gp);
  k_flash<<<dim3(1, 8, 4), 256, 0, stream>>>(W + OQPP, 512, W + OKPP, 512, W + OVT, F, LS);
  k_pma_tail<<<1, 512, 0, stream>>>(F, LS, W + OQPP, W + OPOW, po_b,
                                    fc_w, fc_b, (float*)d_out);
}